// Round 7
// baseline (1319.050 us; speedup 1.0000x reference)
//
#include <hip/hip_runtime.h>
#include <hip/hip_bf16.h>

// ---------------------------------------------------------------------------
// CustomMultiheadAttention on MI355X (gfx950)
//   x = softmax((q Wq^T + bq)(k Wk^T + bk)^T / sqrt(64)) (v Wv^T + bv) Wo^T + bo
// Outputs (concat, fp32): x [4,2048,1024], attn [4,16,2048,2048]
//
// Round-7: attn on 32x32 fragments. QK via mfma_f32_32x32x16_f16 (consistent
// k-mapping trick), PV via classic mfma_f32_32x32x8f16 whose A-layout
// (row=lane&31, k=4*(lane>>5)+j) exactly matches the verified 32x32 C/D
// layout (row=(reg&3)+8*(reg>>2)+4*(lane>>5), col=lane&31): pa = contiguous
// C-reg quads. 4 waves x 32 q-rows = 128 q-rows/block; q is lane-local in
// softmax (no per-tile shfl). launch_bounds(256,4) -> 4 waves/SIMD.
// ---------------------------------------------------------------------------

typedef _Float16 h4 __attribute__((ext_vector_type(4)));
typedef _Float16 h8 __attribute__((ext_vector_type(8)));
typedef float f4 __attribute__((ext_vector_type(4)));
typedef float fx16 __attribute__((ext_vector_type(16)));

#define EMBED 1024
#define HEADS 16
#define HD 64
#define BB 4
#define SS 2048
#define MROWS (BB * SS) // 8192

#define GLD(src, dst)                                                                  \
  __builtin_amdgcn_global_load_lds((const __attribute__((address_space(1))) void*)(src), \
                                   (__attribute__((address_space(3))) void*)(dst), 16, 0, 0)

__device__ inline float fexp2(float x) {
  float r;
  asm("v_exp_f32 %0, %1" : "=v"(r) : "v"(x));
  return r;
}

// ---------------- fused casts fp32 -> fp16 ----------------
__global__ __launch_bounds__(256) void cast3_f32_f16(const float* __restrict__ a,
                                                     const float* __restrict__ b,
                                                     const float* __restrict__ c,
                                                     _Float16* __restrict__ oa,
                                                     _Float16* __restrict__ ob,
                                                     _Float16* __restrict__ oc, int n) {
  const float* in = blockIdx.y == 0 ? a : blockIdx.y == 1 ? b : c;
  _Float16* out = blockIdx.y == 0 ? oa : blockIdx.y == 1 ? ob : oc;
  int i = (blockIdx.x * 256 + threadIdx.x) * 4;
  if (i < n) {
    float4 v = *reinterpret_cast<const float4*>(in + i);
    h4 o = {(_Float16)v.x, (_Float16)v.y, (_Float16)v.z, (_Float16)v.w};
    *reinterpret_cast<h4*>(out + i) = o;
  }
}

__global__ __launch_bounds__(256) void cast4_f32_f16(const float* __restrict__ a,
                                                     const float* __restrict__ b,
                                                     const float* __restrict__ c,
                                                     const float* __restrict__ d,
                                                     _Float16* __restrict__ oa,
                                                     _Float16* __restrict__ ob,
                                                     _Float16* __restrict__ oc,
                                                     _Float16* __restrict__ od, int n) {
  const float* in = blockIdx.y == 0 ? a : blockIdx.y == 1 ? b : blockIdx.y == 2 ? c : d;
  _Float16* out = blockIdx.y == 0 ? oa : blockIdx.y == 1 ? ob : blockIdx.y == 2 ? oc : od;
  int i = (blockIdx.x * 256 + threadIdx.x) * 4;
  if (i < n) {
    float4 v = *reinterpret_cast<const float4*>(in + i);
    h4 o = {(_Float16)v.x, (_Float16)v.y, (_Float16)v.z, (_Float16)v.w};
    *reinterpret_cast<h4*>(out + i) = o;
  }
}

// ---------------- GEMM core: out[m][n] = sum_k A[m][k]*W[n][k] + bias[n] ----
// 128x128 tile, BK=64, 4 waves, 16x16x32 f16 MFMA, global_load_lds w16 with
// XOR swizzle (linear LDS dest + pre-swizzled global source + swizzled read).
template <int OUTF32>
__device__ __forceinline__ void gemm_body(const _Float16* __restrict__ A,
                                          const _Float16* __restrict__ W,
                                          const float* __restrict__ bias,
                                          void* __restrict__ out, char* smem) {
  char* la = smem;
  char* lb = smem + 16384;
  const int t = threadIdx.x;
  const int lane = t & 63;
  const int w = t >> 6;
  const int g = lane >> 4, r16 = lane & 15;
  const int wr = (w >> 1) * 64, wc = (w & 1) * 64;
  const int m0 = blockIdx.x * 128, n0 = blockIdx.y * 128;
  const int p_in_wave = (w << 10) + (lane << 4);

  const char* Ab = (const char*)A;
  const char* Wb = (const char*)W;

  f4 acc[4][4] = {};

  for (int kt = 0; kt < EMBED; kt += 64) {
#pragma unroll
    for (int c = 0; c < 4; c++) {
      int p0 = c * 4096 + p_in_wave;
      int row = p0 >> 7;
      int scol = (p0 & 127) ^ ((row & 7) << 4);
      GLD(Ab + ((size_t)(m0 + row) * EMBED + kt) * 2 + scol, la + c * 4096 + (w << 10));
      GLD(Wb + ((size_t)(n0 + row) * EMBED + kt) * 2 + scol, lb + c * 4096 + (w << 10));
    }
    __syncthreads();
    const int sw = (r16 & 7) << 4;
#pragma unroll
    for (int kk = 0; kk < 2; kk++) {
      h8 af[4], bf[4];
#pragma unroll
      for (int m = 0; m < 4; m++)
        af[m] = *(const h8*)(la + (wr + m * 16 + r16) * 128 + ((kk * 64 + 16 * g) ^ sw));
#pragma unroll
      for (int n = 0; n < 4; n++)
        bf[n] = *(const h8*)(lb + (wc + n * 16 + r16) * 128 + ((kk * 64 + 16 * g) ^ sw));
#pragma unroll
      for (int m = 0; m < 4; m++)
#pragma unroll
        for (int n = 0; n < 4; n++)
          acc[m][n] = __builtin_amdgcn_mfma_f32_16x16x32_f16(af[m], bf[n], acc[m][n], 0, 0, 0);
    }
    __syncthreads();
  }

#pragma unroll
  for (int n = 0; n < 4; n++) {
    int gc = n0 + wc + n * 16 + r16;
    float bv = bias[gc];
#pragma unroll
    for (int m = 0; m < 4; m++) {
#pragma unroll
      for (int r = 0; r < 4; r++) {
        int gr = m0 + wr + m * 16 + 4 * g + r;
        float vv = acc[m][n][r] + bv;
        if (OUTF32)
          reinterpret_cast<float*>(out)[(size_t)gr * EMBED + gc] = vv;
        else
          reinterpret_cast<_Float16*>(out)[(size_t)gr * EMBED + gc] = (_Float16)vv;
      }
    }
  }
}

// QKV projections in one launch: blockIdx.z selects (A, W, bias, out).
__global__ __launch_bounds__(256, 2) void gemm_qkv(const _Float16* qh, const _Float16* kh,
                                                   const _Float16* vh, const _Float16* wq,
                                                   const _Float16* wk, const _Float16* wv,
                                                   const float* bq, const float* bk,
                                                   const float* bv, _Float16* Q, _Float16* K,
                                                   _Float16* V) {
  __shared__ char smem[32768];
  const int z = blockIdx.z;
  const _Float16* A = z == 0 ? qh : z == 1 ? kh : vh;
  const _Float16* W = z == 0 ? wq : z == 1 ? wk : wv;
  const float* bias = z == 0 ? bq : z == 1 ? bk : bv;
  _Float16* out = z == 0 ? Q : z == 1 ? K : V;
  gemm_body<0>(A, W, bias, (void*)out, smem);
}

__global__ __launch_bounds__(256, 2) void gemm_out(const _Float16* __restrict__ A,
                                                   const _Float16* __restrict__ W,
                                                   const float* __restrict__ bias,
                                                   float* __restrict__ out) {
  __shared__ char smem[32768];
  gemm_body<1>(A, W, bias, (void*)out, smem);
}

// ---------------- V transpose: [B,S,H*64] -> per-head [B*H, 64, S] ----------
__global__ __launch_bounds__(256) void transpose_v(const _Float16* __restrict__ Vp,
                                                   _Float16* __restrict__ Vt) {
  __shared__ _Float16 tile[64][72];
  const int s0 = blockIdx.x * 64;
  const int bh = blockIdx.y;
  const int b = bh >> 4, h = bh & 15;
  const int t = threadIdx.x;
#pragma unroll
  for (int it = 0; it < 2; it++) {
    int c = t + it * 256;
    int r = c >> 3, c8 = (c & 7) * 8;
    *reinterpret_cast<float4*>(&tile[r][c8]) =
        *reinterpret_cast<const float4*>(Vp + ((size_t)b * SS + s0 + r) * EMBED + h * HD + c8);
  }
  __syncthreads();
#pragma unroll
  for (int it = 0; it < 2; it++) {
    int c = t + it * 256;
    int d = c >> 3, s8 = (c & 7) * 8;
    h4 lo = {tile[s8 + 0][d], tile[s8 + 1][d], tile[s8 + 2][d], tile[s8 + 3][d]};
    h4 hi = {tile[s8 + 4][d], tile[s8 + 5][d], tile[s8 + 6][d], tile[s8 + 7][d]};
    _Float16* dst = Vt + ((size_t)bh * HD + d) * SS + s0 + s8;
    *reinterpret_cast<h4*>(dst) = lo;
    *reinterpret_cast<h4*>(dst + 4) = hi;
  }
}

// ---------------- fused attention (32x32 fragments) -------------------------
// Grid: (SS/128, B*H). Block 256 = 4 waves; wave w owns q rows
// [qt*128 + 32w, +32). Swapped QK^T: C holds S[key=crow][q=lane&31] where
// crow = (reg&3)+8*(reg>>2)+4*(lane>>5). q is lane-local -> pass-1 softmax
// sum needs no per-tile shuffles. PV: pa = C reg quad [4k8..4k8+3] (keys
// 8k8+4hi+0..3) feeds mfma_32x32x8f16 A (k=4hi+j) directly.
__global__ __launch_bounds__(256, 4) void attn_fused(const _Float16* __restrict__ Q,
                                                     const _Float16* __restrict__ K,
                                                     const _Float16* __restrict__ Vt,
                                                     float* __restrict__ attn_out,
                                                     _Float16* __restrict__ Oh) {
  __shared__ char smem[32768];
  const int t = threadIdx.x;
  const int lane = t & 63;
  const int w = t >> 6;
  const int c31 = lane & 31;
  const int hi = lane >> 5;
  const int qt = blockIdx.x;
  const int bh = blockIdx.y;
  const int b = bh >> 4, h = bh & 15;
  const int q0 = qt * 128 + w * 32;
  const int sw = (c31 & 7) << 4;

  const float CC = 0.1803368801f;  // (1/sqrt(64)) * log2(e)

  const char* kbase = (const char*)K + ((size_t)b * SS * EMBED + h * HD) * 2;
  const char* vtbase = (const char*)Vt + (size_t)bh * HD * SS * 2;

  // per-lane staging source precompute (two 4KB chunks per 8KB tile)
  const int p_in_wave = (w << 10) + (lane << 4);
  int srow[2], scol[2];
#pragma unroll
  for (int c = 0; c < 2; c++) {
    int p0 = c * 4096 + p_in_wave;
    srow[c] = p0 >> 7;
    scol[c] = (p0 & 127) ^ ((srow[c] & 7) << 4);
  }

  // K buffers at smem+{0,8192}, V buffers at smem+{16384,24576}
#define STAGE_K(boff, kb)                                                              \
  {                                                                                    \
    _Pragma("unroll") for (int c = 0; c < 2; c++)                                      \
        GLD(kbase + (size_t)((kb) * 64 + srow[c]) * 2048 + scol[c],                    \
            smem + (boff) + c * 4096 + (w << 10));                                     \
  }
#define STAGE_V(boff, kb)                                                              \
  {                                                                                    \
    _Pragma("unroll") for (int c = 0; c < 2; c++)                                      \
        GLD(vtbase + (size_t)srow[c] * 4096 + (kb) * 128 + scol[c],                    \
            smem + (boff) + c * 4096 + (w << 10));                                     \
  }

  // hoist Q fragments (B-operand: col=q=c31, slot (hi,j) -> d = kk*16+8hi+j)
  h8 qf[4];
  const _Float16* qptr = Q + ((size_t)b * SS + q0 + c31) * EMBED + h * HD;
#pragma unroll
  for (int kk = 0; kk < 4; kk++)
    qf[kk] = *reinterpret_cast<const h8*>(qptr + kk * 16 + 8 * hi);

  // ---- pass 1: lane-local l accumulation (q = c31 for both hi halves) ----
  float lloc = 0.0f;
  STAGE_K(0, 0);
  __syncthreads();
  for (int kb = 0; kb < 32; kb++) {
    const char* cur = smem + (kb & 1) * 8192;
    if (kb < 31) STAGE_K(((kb + 1) & 1) * 8192, kb + 1);
    __builtin_amdgcn_s_setprio(1);
#pragma unroll
    for (int kb32 = 0; kb32 < 2; kb32++) {
      fx16 sf = {0, 0, 0, 0, 0, 0, 0, 0, 0, 0, 0, 0, 0, 0, 0, 0};
#pragma unroll
      for (int kk = 0; kk < 4; kk++) {
        h8 af = *(const h8*)(cur + (kb32 * 32 + c31) * 128 + ((kk * 32 + 16 * hi) ^ sw));
        sf = __builtin_amdgcn_mfma_f32_32x32x16_f16(af, qf[kk], sf, 0, 0, 0);
      }
      __builtin_amdgcn_s_setprio(0);
#pragma unroll
      for (int r = 0; r < 16; r++) lloc += fexp2(sf[r] * CC);
      __builtin_amdgcn_s_setprio(1);
    }
    __builtin_amdgcn_s_setprio(0);
    __syncthreads();
  }
  lloc += __shfl_xor(lloc, 32, 64);
  const float lgr = -__log2f(lloc);

  // ---- pass 2: recompute, write normalized attn, accumulate PV ----
  fx16 oaccA = {0, 0, 0, 0, 0, 0, 0, 0, 0, 0, 0, 0, 0, 0, 0, 0};
  fx16 oaccB = {0, 0, 0, 0, 0, 0, 0, 0, 0, 0, 0, 0, 0, 0, 0, 0};
  float* arow = attn_out + ((size_t)bh * SS + q0 + c31) * SS;

  STAGE_K(0, 0);
  STAGE_V(16384, 0);
  __syncthreads();
  for (int kb = 0; kb < 32; kb++) {
    const char* ck = smem + (kb & 1) * 8192;
    const char* cv = smem + 16384 + (kb & 1) * 8192;
    if (kb < 31) {
      STAGE_K(((kb + 1) & 1) * 8192, kb + 1);
      STAGE_V(16384 + ((kb + 1) & 1) * 8192, kb + 1);
    }
    __builtin_amdgcn_s_setprio(1);
#pragma unroll
    for (int kb32 = 0; kb32 < 2; kb32++) {
      fx16 sf = {0, 0, 0, 0, 0, 0, 0, 0, 0, 0, 0, 0, 0, 0, 0, 0};
#pragma unroll
      for (int kk = 0; kk < 4; kk++) {
        h8 af = *(const h8*)(ck + (kb32 * 32 + c31) * 128 + ((kk * 32 + 16 * hi) ^ sw));
        sf = __builtin_amdgcn_mfma_f32_32x32x16_f16(af, qf[kk], sf, 0, 0, 0);
      }
      __builtin_amdgcn_s_setprio(0);
      float a[16];
#pragma unroll
      for (int r = 0; r < 16; r++) a[r] = fexp2(fmaf(sf[r], CC, lgr));
      __builtin_amdgcn_s_setprio(1);
#pragma unroll
      for (int k8 = 0; k8 < 4; k8++) {
        f4 st = {a[4 * k8 + 0], a[4 * k8 + 1], a[4 * k8 + 2], a[4 * k8 + 3]};
        __builtin_nontemporal_store(
            st, reinterpret_cast<f4*>(arow + kb * 64 + kb32 * 32 + k8 * 8 + 4 * hi));
        h4 pa4 = {(_Float16)a[4 * k8 + 0], (_Float16)a[4 * k8 + 1], (_Float16)a[4 * k8 + 2],
                  (_Float16)a[4 * k8 + 3]};
        // V B-frag: slot (hi,j) -> key = kb32*32 + k8*8 + 4hi + j, col=d
        h4 vf0 = *(const h4*)(cv + (0 * 32 + c31) * 128 +
                              ((kb32 * 64 + k8 * 16 + 8 * hi) ^ sw));
        h4 vf1 = *(const h4*)(cv + (1 * 32 + c31) * 128 +
                              ((kb32 * 64 + k8 * 16 + 8 * hi) ^ sw));
        oaccA = __builtin_amdgcn_mfma_f32_32x32x8f16(pa4, vf0, oaccA, 0, 0, 0);
        oaccB = __builtin_amdgcn_mfma_f32_32x32x8f16(pa4, vf1, oaccB, 0, 0, 0);
      }
    }
    __builtin_amdgcn_s_setprio(0);
    __syncthreads();
  }

  // write O (fp16): O[q=crow(r,hi)][d = 32*dblk + c31]
#pragma unroll
  for (int r = 0; r < 16; r++) {
    int qrow = q0 + (r & 3) + 8 * (r >> 2) + 4 * hi;
    _Float16* orow = Oh + ((size_t)b * SS + qrow) * EMBED + h * HD;
    orow[c31] = (_Float16)oaccA[r];
    orow[32 + c31] = (_Float16)oaccB[r];
  }
#undef STAGE_K
#undef STAGE_V
}

// ---------------------------------------------------------------------------
extern "C" void kernel_launch(void* const* d_in, const int* in_sizes, int n_in,
                              void* d_out, int out_size, void* d_ws, size_t ws_size,
                              hipStream_t stream) {
  const float* q  = (const float*)d_in[0];
  const float* k  = (const float*)d_in[1];
  const float* v  = (const float*)d_in[2];
  const float* Wq = (const float*)d_in[3];
  const float* bq = (const float*)d_in[4];
  const float* Wk = (const float*)d_in[5];
  const float* bk = (const float*)d_in[6];
  const float* Wv = (const float*)d_in[7];
  const float* bv = (const float*)d_in[8];
  const float* Wo = (const float*)d_in[9];
  const float* bo = (const float*)d_in[10];

  const size_t NW = (size_t)EMBED * EMBED;   // 1,048,576
  const size_t NX = (size_t)MROWS * EMBED;   // 8,388,608

  if (ws_size < (4 * NW + 6 * NX) * sizeof(_Float16)) return;  // loud failure
  _Float16* ws  = (_Float16*)d_ws;
  _Float16* wqh = ws;
  _Float16* wkh = wqh + NW;
  _Float16* wvh = wkh + NW;
  _Float16* woh = wvh + NW;
  _Float16* qh  = woh + NW;
  _Float16* kh  = qh + NX;
  _Float16* vh  = kh + NX;
  _Float16* Qh  = vh + NX;
  _Float16* Kh  = Qh + NX;
  _Float16* Vph = Kh + NX;
  _Float16* VtA = qh;  // alias: qh dead after Q projection
  _Float16* OhA = kh;  // alias: kh dead after K projection

  float* xout = (float*)d_out;
  float* attn = xout + NX;

  cast3_f32_f16<<<dim3((NX / 4 + 255) / 256, 3), dim3(256), 0, stream>>>(q, k, v, qh, kh, vh,
                                                                         (int)NX);
  cast4_f32_f16<<<dim3((NW / 4 + 255) / 256, 4), dim3(256), 0, stream>>>(
      Wq, Wk, Wv, Wo, wqh, wkh, wvh, woh, (int)NW);

  dim3 ggrid(MROWS / 128, EMBED / 128), gblk(256);
  gemm_qkv<<<dim3(MROWS / 128, EMBED / 128, 3), gblk, 0, stream>>>(qh, kh, vh, wqh, wkh, wvh,
                                                                   bq, bk, bv, Qh, Kh, Vph);

  transpose_v<<<dim3(SS / 64, BB * HEADS), dim3(256), 0, stream>>>(Vph, VtA);

  attn_fused<<<dim3(SS / 128, BB * HEADS), dim3(256), 0, stream>>>(Qh, Kh, VtA, attn, OhA);

  gemm_out<<<ggrid, gblk, 0, stream>>>(OhA, woh, bo, xout);
}

// Round 8
// 545.221 us; speedup vs baseline: 2.4193x; 2.4193x over previous
//
#include <hip/hip_runtime.h>
#include <hip/hip_bf16.h>

// ---------------------------------------------------------------------------
// CustomMultiheadAttention on MI355X (gfx950)
//   x = softmax((q Wq^T + bq)(k Wk^T + bk)^T / sqrt(64)) (v Wv^T + bv) Wo^T + bo
// Outputs (concat, fp32): x [4,2048,1024], attn [4,16,2048,2048]
//
// Round-8: revert attn to the proven 16x16 round-5 structure; split into
// pass1 (denominator only, 16KB LDS) + pass2 (attn write + PV) kernels for
// occupancy + separate counters; V-projection epilogue writes Vt directly in
// key-permuted per-head layout so the PV B-fragment is a single ds_read_b128;
// transpose kernel eliminated.
// ---------------------------------------------------------------------------

typedef _Float16 h4 __attribute__((ext_vector_type(4)));
typedef _Float16 h8 __attribute__((ext_vector_type(8)));
typedef float f4 __attribute__((ext_vector_type(4)));

#define EMBED 1024
#define HEADS 16
#define HD 64
#define BB 4
#define SS 2048
#define MROWS (BB * SS) // 8192

#define GLD(src, dst)                                                                  \
  __builtin_amdgcn_global_load_lds((const __attribute__((address_space(1))) void*)(src), \
                                   (__attribute__((address_space(3))) void*)(dst), 16, 0, 0)

__device__ inline float fexp2(float x) {
  float r;
  asm("v_exp_f32 %0, %1" : "=v"(r) : "v"(x));
  return r;
}

// ---------------- fused casts fp32 -> fp16 ----------------
__global__ __launch_bounds__(256) void cast3_f32_f16(const float* __restrict__ a,
                                                     const float* __restrict__ b,
                                                     const float* __restrict__ c,
                                                     _Float16* __restrict__ oa,
                                                     _Float16* __restrict__ ob,
                                                     _Float16* __restrict__ oc, int n) {
  const float* in = blockIdx.y == 0 ? a : blockIdx.y == 1 ? b : c;
  _Float16* out = blockIdx.y == 0 ? oa : blockIdx.y == 1 ? ob : oc;
  int i = (blockIdx.x * 256 + threadIdx.x) * 4;
  if (i < n) {
    float4 v = *reinterpret_cast<const float4*>(in + i);
    h4 o = {(_Float16)v.x, (_Float16)v.y, (_Float16)v.z, (_Float16)v.w};
    *reinterpret_cast<h4*>(out + i) = o;
  }
}

__global__ __launch_bounds__(256) void cast4_f32_f16(const float* __restrict__ a,
                                                     const float* __restrict__ b,
                                                     const float* __restrict__ c,
                                                     const float* __restrict__ d,
                                                     _Float16* __restrict__ oa,
                                                     _Float16* __restrict__ ob,
                                                     _Float16* __restrict__ oc,
                                                     _Float16* __restrict__ od, int n) {
  const float* in = blockIdx.y == 0 ? a : blockIdx.y == 1 ? b : blockIdx.y == 2 ? c : d;
  _Float16* out = blockIdx.y == 0 ? oa : blockIdx.y == 1 ? ob : blockIdx.y == 2 ? oc : od;
  int i = (blockIdx.x * 256 + threadIdx.x) * 4;
  if (i < n) {
    float4 v = *reinterpret_cast<const float4*>(in + i);
    h4 o = {(_Float16)v.x, (_Float16)v.y, (_Float16)v.z, (_Float16)v.w};
    *reinterpret_cast<h4*>(out + i) = o;
  }
}

// ---------------- GEMM core: out[m][n] = sum_k A[m][k]*W[n][k] + bias[n] ----
// 128x128 tile, BK=64, 4 waves, 16x16x32 f16 MFMA, global_load_lds w16 with
// XOR swizzle. MODE: 0 = f16 row-major, 1 = f32 row-major, 2 = f16 V
// transposed per-head key-permuted layout Vt2[bh][d][2048] with key order
// within each 32-chunk: pos(g,half,j) = g*8 + half*4 + j for key = 16*half+4g+j.
template <int MODE>
__device__ __forceinline__ void gemm_body(const _Float16* __restrict__ A,
                                          const _Float16* __restrict__ W,
                                          const float* __restrict__ bias,
                                          void* __restrict__ out, char* smem) {
  char* la = smem;
  char* lb = smem + 16384;
  const int t = threadIdx.x;
  const int lane = t & 63;
  const int w = t >> 6;
  const int g = lane >> 4, r16 = lane & 15;
  const int wr = (w >> 1) * 64, wc = (w & 1) * 64;
  const int m0 = blockIdx.x * 128, n0 = blockIdx.y * 128;
  const int p_in_wave = (w << 10) + (lane << 4);

  const char* Ab = (const char*)A;
  const char* Wb = (const char*)W;

  f4 acc[4][4] = {};

  for (int kt = 0; kt < EMBED; kt += 64) {
#pragma unroll
    for (int c = 0; c < 4; c++) {
      int p0 = c * 4096 + p_in_wave;
      int row = p0 >> 7;
      int scol = (p0 & 127) ^ ((row & 7) << 4);
      GLD(Ab + ((size_t)(m0 + row) * EMBED + kt) * 2 + scol, la + c * 4096 + (w << 10));
      GLD(Wb + ((size_t)(n0 + row) * EMBED + kt) * 2 + scol, lb + c * 4096 + (w << 10));
    }
    __syncthreads();
    const int sw = (r16 & 7) << 4;
#pragma unroll
    for (int kk = 0; kk < 2; kk++) {
      h8 af[4], bf[4];
#pragma unroll
      for (int m = 0; m < 4; m++)
        af[m] = *(const h8*)(la + (wr + m * 16 + r16) * 128 + ((kk * 64 + 16 * g) ^ sw));
#pragma unroll
      for (int n = 0; n < 4; n++)
        bf[n] = *(const h8*)(lb + (wc + n * 16 + r16) * 128 + ((kk * 64 + 16 * g) ^ sw));
#pragma unroll
      for (int m = 0; m < 4; m++)
#pragma unroll
        for (int n = 0; n < 4; n++)
          acc[m][n] = __builtin_amdgcn_mfma_f32_16x16x32_f16(af[m], bf[n], acc[m][n], 0, 0, 0);
    }
    __syncthreads();
  }

#pragma unroll
  for (int n = 0; n < 4; n++) {
    int gc = n0 + wc + n * 16 + r16;
    float bv = bias[gc];
#pragma unroll
    for (int m = 0; m < 4; m++) {
#pragma unroll
      for (int r = 0; r < 4; r++) {
        int gr = m0 + wr + m * 16 + 4 * g + r;
        float vv = acc[m][n][r] + bv;
        if (MODE == 1) {
          reinterpret_cast<float*>(out)[(size_t)gr * EMBED + gc] = vv;
        } else if (MODE == 0) {
          reinterpret_cast<_Float16*>(out)[(size_t)gr * EMBED + gc] = (_Float16)vv;
        } else {
          // Vt2[bh][d][s'] : bh = (gr>>11)*16 + (gc>>6), d = gc&63
          int s = gr & 2047;
          int s32 = s & 31;
          int gg = (s32 >> 2) & 3, jj = s32 & 3, hf = s32 >> 4;
          int s2 = (s & ~31) + gg * 8 + hf * 4 + jj;
          size_t bh = (size_t)((gr >> 11) * 16 + (gc >> 6));
          reinterpret_cast<_Float16*>(out)[(bh * 64 + (gc & 63)) * 2048 + s2] = (_Float16)vv;
        }
      }
    }
  }
}

// QKV projections in one launch: blockIdx.z selects (A, W, bias, out).
__global__ __launch_bounds__(256, 2) void gemm_qkv(const _Float16* qh, const _Float16* kh,
                                                   const _Float16* vh, const _Float16* wq,
                                                   const _Float16* wk, const _Float16* wv,
                                                   const float* bq, const float* bk,
                                                   const float* bv, _Float16* Q, _Float16* K,
                                                   _Float16* Vt2) {
  __shared__ char smem[32768];
  const int z = blockIdx.z;
  if (z == 2) {
    gemm_body<2>(vh, wv, bv, (void*)Vt2, smem);
  } else {
    gemm_body<0>(z ? kh : qh, z ? wk : wq, z ? bk : bq, (void*)(z ? K : Q), smem);
  }
}

__global__ __launch_bounds__(256, 2) void gemm_out(const _Float16* __restrict__ A,
                                                   const _Float16* __restrict__ W,
                                                   const float* __restrict__ bias,
                                                   float* __restrict__ out) {
  __shared__ char smem[32768];
  gemm_body<1>(A, W, bias, (void*)out, smem);
}

// ---------------- attention pass 1: lgr = -log2(sum_k exp2(S*CC)) ----------
// Grid: (SS/64, B*H). Block 256 = 4 waves; wave w owns q rows [qt*64+16w,+16).
// Swapped QK^T (16x16x32): lane holds S[key=4g+r][q=r16]. K double-buffered
// (16 KB LDS), one barrier/iter; no V, no stores -> high occupancy.
__global__ __launch_bounds__(256, 2) void attn_pass1(const _Float16* __restrict__ Q,
                                                     const _Float16* __restrict__ K,
                                                     float* __restrict__ lbuf) {
  __shared__ char smem[16384];
  const int t = threadIdx.x;
  const int lane = t & 63;
  const int w = t >> 6;
  const int g = lane >> 4, r16 = lane & 15;
  const int qt = blockIdx.x;
  const int bh = blockIdx.y;
  const int b = bh >> 4, h = bh & 15;
  const int qrow = qt * 64 + w * 16 + r16;
  const int p_in_wave = (w << 10) + (lane << 4);
  const int sw = (r16 & 7) << 4;
  const float CC = 0.1803368801f;  // (1/sqrt(64)) * log2(e)

  const char* kbase = (const char*)K + ((size_t)b * SS * EMBED + h * HD) * 2;

  int srow[2], scol[2];
#pragma unroll
  for (int c = 0; c < 2; c++) {
    int p0 = c * 4096 + p_in_wave;
    srow[c] = p0 >> 7;
    scol[c] = (p0 & 127) ^ ((srow[c] & 7) << 4);
  }

#define STAGE_K1(boff, kb)                                                             \
  {                                                                                    \
    _Pragma("unroll") for (int c = 0; c < 2; c++)                                      \
        GLD(kbase + (size_t)((kb) * 64 + srow[c]) * 2048 + scol[c],                    \
            smem + (boff) + c * 4096 + (w << 10));                                     \
  }

  h8 qf[2];
  const _Float16* qptr = Q + ((size_t)b * SS + qrow) * EMBED + h * HD;
#pragma unroll
  for (int kk = 0; kk < 2; kk++)
    qf[kk] = *reinterpret_cast<const h8*>(qptr + kk * 32 + 8 * g);

  float l_run = 0.0f;
  STAGE_K1(0, 0);
  __syncthreads();
  for (int kb = 0; kb < 32; kb++) {
    const char* cur = smem + (kb & 1) * 8192;
    if (kb < 31) STAGE_K1(((kb + 1) & 1) * 8192, kb + 1);
    float s = 0.f;
    __builtin_amdgcn_s_setprio(1);
#pragma unroll
    for (int kf = 0; kf < 4; kf++) {
      f4 sf = {0.f, 0.f, 0.f, 0.f};
#pragma unroll
      for (int kk = 0; kk < 2; kk++) {
        h8 af = *(const h8*)(cur + (kf * 16 + r16) * 128 + ((kk * 64 + 16 * g) ^ sw));
        sf = __builtin_amdgcn_mfma_f32_16x16x32_f16(af, qf[kk], sf, 0, 0, 0);
      }
#pragma unroll
      for (int r = 0; r < 4; r++) s += fexp2(sf[r] * CC);
    }
    __builtin_amdgcn_s_setprio(0);
    s += __shfl_xor(s, 16, 64);
    s += __shfl_xor(s, 32, 64);
    l_run += s;
    __syncthreads();
  }
  if (lane < 16) lbuf[(size_t)bh * SS + qrow] = -__log2f(l_run);
#undef STAGE_K1
}

// ---------------- attention pass 2: attn write + PV --------------------------
// Same geometry as pass 1; K and Vt2 double-buffered (32 KB LDS).
// a = exp2(fma(S, CC, lgr)); nontemporal f4 stores (4 g-lanes cover a full
// 64B line per instruction); PV B-frag = single ds_read_b128 (Vt2 permuted).
__global__ __launch_bounds__(256, 2) void attn_pass2(const _Float16* __restrict__ Q,
                                                     const _Float16* __restrict__ K,
                                                     const _Float16* __restrict__ Vt,
                                                     const float* __restrict__ lbuf,
                                                     float* __restrict__ attn_out,
                                                     _Float16* __restrict__ Oh) {
  __shared__ char smem[32768];
  const int t = threadIdx.x;
  const int lane = t & 63;
  const int w = t >> 6;
  const int g = lane >> 4, r16 = lane & 15;
  const int qt = blockIdx.x;
  const int bh = blockIdx.y;
  const int b = bh >> 4, h = bh & 15;
  const int qrow = qt * 64 + w * 16 + r16;
  const int p_in_wave = (w << 10) + (lane << 4);
  const int sw = (r16 & 7) << 4;
  const float CC = 0.1803368801f;

  const char* kbase = (const char*)K + ((size_t)b * SS * EMBED + h * HD) * 2;
  const char* vtbase = (const char*)Vt + (size_t)bh * HD * SS * 2;

  int srow[2], scol[2];
#pragma unroll
  for (int c = 0; c < 2; c++) {
    int p0 = c * 4096 + p_in_wave;
    srow[c] = p0 >> 7;
    scol[c] = (p0 & 127) ^ ((srow[c] & 7) << 4);
  }

#define STAGE_K2(boff, kb)                                                             \
  {                                                                                    \
    _Pragma("unroll") for (int c = 0; c < 2; c++)                                      \
        GLD(kbase + (size_t)((kb) * 64 + srow[c]) * 2048 + scol[c],                    \
            smem + (boff) + c * 4096 + (w << 10));                                     \
  }
#define STAGE_V2(boff, kb)                                                             \
  {                                                                                    \
    _Pragma("unroll") for (int c = 0; c < 2; c++)                                      \
        GLD(vtbase + (size_t)srow[c] * 4096 + (kb) * 128 + scol[c],                    \
            smem + (boff) + c * 4096 + (w << 10));                                     \
  }

  h8 qf[2];
  const _Float16* qptr = Q + ((size_t)b * SS + qrow) * EMBED + h * HD;
#pragma unroll
  for (int kk = 0; kk < 2; kk++)
    qf[kk] = *reinterpret_cast<const h8*>(qptr + kk * 32 + 8 * g);

  const float lgr = lbuf[(size_t)bh * SS + qrow];

  f4 oacc[4] = {};
  float* arow = attn_out + ((size_t)bh * SS + qrow) * SS;

  STAGE_K2(0, 0);
  STAGE_V2(16384, 0);
  __syncthreads();
  for (int kb = 0; kb < 32; kb++) {
    const char* ck = smem + (kb & 1) * 8192;
    const char* cv = smem + 16384 + (kb & 1) * 8192;
    if (kb < 31) {
      STAGE_K2(((kb + 1) & 1) * 8192, kb + 1);
      STAGE_V2(16384 + ((kb + 1) & 1) * 8192, kb + 1);
    }
    h4 pa[4];
    __builtin_amdgcn_s_setprio(1);
#pragma unroll
    for (int kf = 0; kf < 4; kf++) {
      f4 sf = {0.f, 0.f, 0.f, 0.f};
#pragma unroll
      for (int kk = 0; kk < 2; kk++) {
        h8 af = *(const h8*)(ck + (kf * 16 + r16) * 128 + ((kk * 64 + 16 * g) ^ sw));
        sf = __builtin_amdgcn_mfma_f32_16x16x32_f16(af, qf[kk], sf, 0, 0, 0);
      }
      __builtin_amdgcn_s_setprio(0);
      float a0 = fexp2(fmaf(sf[0], CC, lgr));
      float a1 = fexp2(fmaf(sf[1], CC, lgr));
      float a2 = fexp2(fmaf(sf[2], CC, lgr));
      float a3 = fexp2(fmaf(sf[3], CC, lgr));
      f4 st = {a0, a1, a2, a3};
      __builtin_nontemporal_store(st, reinterpret_cast<f4*>(arow + kb * 64 + kf * 16 + 4 * g));
      pa[kf] = h4{(_Float16)a0, (_Float16)a1, (_Float16)a2, (_Float16)a3};
      __builtin_amdgcn_s_setprio(1);
    }
    // PV: A k-map j<4 -> 4g+j, j>=4 -> 16+4g+j; Vt2 permuted so B-frag is
    // one b128 at halves kf2*32 + g*8 .. +8.
#pragma unroll
    for (int kf2 = 0; kf2 < 2; kf2++) {
      h8 pa8 = __builtin_shufflevector(pa[2 * kf2], pa[2 * kf2 + 1], 0, 1, 2, 3, 4, 5, 6, 7);
#pragma unroll
      for (int dt = 0; dt < 4; dt++) {
        h8 bf8 = *(const h8*)(cv + (dt * 16 + r16) * 128 + ((kf2 * 64 + 16 * g) ^ sw));
        oacc[dt] = __builtin_amdgcn_mfma_f32_16x16x32_f16(pa8, bf8, oacc[dt], 0, 0, 0);
      }
    }
    __builtin_amdgcn_s_setprio(0);
    __syncthreads();
  }

  const int orow0 = qt * 64 + w * 16;
#pragma unroll
  for (int dt = 0; dt < 4; dt++) {
#pragma unroll
    for (int r = 0; r < 4; r++) {
      Oh[((size_t)b * SS + orow0 + 4 * g + r) * EMBED + h * HD + dt * 16 + r16] =
          (_Float16)oacc[dt][r];
    }
  }
#undef STAGE_K2
#undef STAGE_V2
}

// ---------------------------------------------------------------------------
extern "C" void kernel_launch(void* const* d_in, const int* in_sizes, int n_in,
                              void* d_out, int out_size, void* d_ws, size_t ws_size,
                              hipStream_t stream) {
  const float* q  = (const float*)d_in[0];
  const float* k  = (const float*)d_in[1];
  const float* v  = (const float*)d_in[2];
  const float* Wq = (const float*)d_in[3];
  const float* bq = (const float*)d_in[4];
  const float* Wk = (const float*)d_in[5];
  const float* bk = (const float*)d_in[6];
  const float* Wv = (const float*)d_in[7];
  const float* bv = (const float*)d_in[8];
  const float* Wo = (const float*)d_in[9];
  const float* bo = (const float*)d_in[10];

  const size_t NW = (size_t)EMBED * EMBED;   // 1,048,576
  const size_t NX = (size_t)MROWS * EMBED;   // 8,388,608

  if (ws_size < (4 * NW + 6 * NX) * sizeof(_Float16)) return;  // loud failure
  _Float16* ws  = (_Float16*)d_ws;
  _Float16* wqh = ws;
  _Float16* wkh = wqh + NW;
  _Float16* wvh = wkh + NW;
  _Float16* woh = wvh + NW;
  _Float16* qh  = woh + NW;
  _Float16* kh  = qh + NX;
  _Float16* vh  = kh + NX;
  _Float16* Qh  = vh + NX;
  _Float16* Kh  = Qh + NX;
  _Float16* Vt2 = Kh + NX;          // V directly in transposed-permuted layout
  _Float16* OhA = kh;               // alias: kh dead after K projection
  float* lbuf   = (float*)vh;       // alias: vh dead after V projection (512 KB)

  float* xout = (float*)d_out;
  float* attn = xout + NX;

  cast3_f32_f16<<<dim3((NX / 4 + 255) / 256, 3), dim3(256), 0, stream>>>(q, k, v, qh, kh, vh,
                                                                         (int)NX);
  cast4_f32_f16<<<dim3((NW / 4 + 255) / 256, 4), dim3(256), 0, stream>>>(
      Wq, Wk, Wv, Wo, wqh, wkh, wvh, woh, (int)NW);

  dim3 ggrid(MROWS / 128, EMBED / 128), gblk(256);
  gemm_qkv<<<dim3(MROWS / 128, EMBED / 128, 3), gblk, 0, stream>>>(qh, kh, vh, wqh, wkh, wvh,
                                                                   bq, bk, bv, Qh, Kh, Vt2);

  attn_pass1<<<dim3(SS / 64, BB * HEADS), dim3(256), 0, stream>>>(Qh, Kh, lbuf);

  attn_pass2<<<dim3(SS / 64, BB * HEADS), dim3(256), 0, stream>>>(Qh, Kh, Vt2, lbuf, attn,
                                                                  OhA);

  gemm_out<<<ggrid, gblk, 0, stream>>>(OhA, woh, bo, xout);
}